// Round 14
// baseline (248.300 us; speedup 1.0000x reference)
//
#include <hip/hip_runtime.h>

#define V 255
#define L 16
#define P 8
#define CLIPV 10.0f

typedef __attribute__((ext_vector_type(4))) float f32x4;

__device__ __forceinline__ f32x4 splat4(float a) { return (f32x4){a, a, a, a}; }
__device__ __forceinline__ f32x4 fma4(f32x4 a, f32x4 b, f32x4 c) {
    return __builtin_elementwise_fma(a, b, c);
}

// tanh(0.5 * clip(s,-10,10)) = 1 - 2/(exp(clip(s))+1), then zsub (0 -> 1)
__device__ __forceinline__ f32x4 tanh_zsub4(f32x4 s) {
    f32x4 t = __builtin_elementwise_min(
                  __builtin_elementwise_max(s, splat4(-CLIPV)), splat4(CLIPV));
    f32x4 r;
#pragma unroll
    for (int c = 0; c < 4; ++c) {
        float e = __expf(t[c]);
        float o = 1.0f - __fdividef(2.0f, e + 1.0f);
        r[c] = (o == 0.0f) ? 1.0f : o;
    }
    return r;
}

// Four (b,p) units per thread in f32x4. One LDS b128 op serves 4 units ->
// per-unit LDS/addr issue slots ~halve vs f32x2. Fused even+odd via
// cr(rc(i))==i (r9 algebra); padded stride-256 LDS (thread 255 = live dummy,
// no predication); t-loop fully unrolled; matvec in 4-wide chunks with
// immediate publish (VGPR control); own-e re-read from LDS (saves 64 VGPR).
template <int MODE>
__global__ __launch_bounds__(256, 2) void bpz_kernel(
    const float* __restrict__ x,
    const float* __restrict__ oddw_v,
    const float* __restrict__ oddw_e,
    const float* __restrict__ w_e_out,
    const int*   __restrict__ perma,
    const int*   __restrict__ rc_idx,
    const int*   __restrict__ cr_idx,
    float* __restrict__ eo_ws,     // MODE 0
    const int* __restrict__ invp,  // MODE 1
    float* __restrict__ out)       // MODE 1
{
    __shared__ f32x4 OO[L * 256];   // zsub'd odd outputs, col-major, 64 KB
    __shared__ f32x4 TOT[256];      // per-row products, 4 KB

    const int tid = threadIdx.x;
    const int blk = blockIdx.x;          // quad id: 2 per batch row
    const int b     = blk >> 1;
    const int pbase = (blk & 1) * 4;
    const int v  = tid;                  // 0..255; 255 = dummy (full duty)
    const int vi = (v < V) ? v : (V - 1);
    const int vc = (v < V) ? (v + 1) : V;

    // x values for 4 units
    f32x4 xv;
    {
        const float* xrow = x + b * (V + 1);
#pragma unroll
        for (int c = 0; c < 4; ++c)
            xv[c] = xrow[perma[(pbase + c) * (V + 1) + vc]];
    }

    // packed element indices: lo12 = OO elem (cr-gather), hi16 = TOT elem
    unsigned pk[L];
    {
        const int4* rc4 = (const int4*)(rc_idx + vi * L);
        const int4* cr4 = (const int4*)(cr_idx + vi * L);
#pragma unroll
        for (int i = 0; i < 4; ++i) {
            int4 a = rc4[i];
            int4 c = cr4[i];
            pk[4*i+0] = ((unsigned)(a.x >> 4) << 16) | (((c.x & 15) << 8) | (c.x >> 4));
            pk[4*i+1] = ((unsigned)(a.y >> 4) << 16) | (((c.y & 15) << 8) | (c.y >> 4));
            pk[4*i+2] = ((unsigned)(a.z >> 4) << 16) | (((c.z & 15) << 8) | (c.z >> 4));
            pk[4*i+3] = ((unsigned)(a.w >> 4) << 16) | (((c.w & 15) << 8) | (c.w >> 4));
        }
    }

    // ---- t=0 odd layer (message==0 -> rank-1), zsub'd ----
    f32x4 ev[L];
#pragma unroll
    for (int m = 0; m < L; ++m)
        ev[m] = tanh_zsub4(xv * oddw_v[m]);        // uniform s_load

    // publish t=0 (t>=1 publishes inside the matvec chunks)
#pragma unroll
    for (int m = 0; m < L; ++m) OO[(m << 8) + v] = ev[m];

#pragma unroll
    for (int t = 0; t < 5; ++t) {
        __syncthreads();   // OO complete

        // ---- cr-gather + tree product -> row total ----
        {
            f32x4 t0 = OO[pk[0] & 0xfffu], t1 = OO[pk[1] & 0xfffu];
            f32x4 t2 = OO[pk[2] & 0xfffu], t3 = OO[pk[3] & 0xfffu];
#pragma unroll
            for (int l = 4; l < L; l += 4) {
                t0 = t0 * OO[pk[l + 0] & 0xfffu];
                t1 = t1 * OO[pk[l + 1] & 0xfffu];
                t2 = t2 * OO[pk[l + 2] & 0xfffu];
                t3 = t3 * OO[pk[l + 3] & 0xfffu];
            }
            TOT[v] = (t0 * t1) * (t2 * t3);
        }
        __syncthreads();   // TOT complete; OO stable until matvec publish

        // ---- fused logratio (own e re-read from LDS): r = T/e;
        // log((1+r)/(1-r+1e-9)+1e-9) == log((e+T)/(e-T+1e-9*e)) to ~1e-6
        // (|r| <= tanh(5)^15 ~ 0.9986; t=0 clip(r,+-10) is an identity). ----
#pragma unroll
        for (int l = 0; l < L; ++l) {
            f32x4 e  = OO[(l << 8) + v];
            f32x4 Tl = TOT[pk[l] >> 16];
            f32x4 num = e + Tl;
            f32x4 den = fma4(e, splat4(1e-9f), e - Tl);
            f32x4 o;
#pragma unroll
            for (int c = 0; c < 4; ++c)
                o[c] = __logf(__fdividef(num[c], den[c]));
            ev[l] = o;
        }

        if (t < 4) {
            // ---- odd matvec in 4-wide chunks, publish per chunk ----
            const float* __restrict__ wv = oddw_v + (t + 1) * L;
            const float* __restrict__ wm = oddw_e + (t + 1) * (L * L);
#pragma unroll
            for (int ch = 0; ch < 4; ++ch) {
                f32x4 s0 = xv * wv[ch * 4 + 0];
                f32x4 s1 = xv * wv[ch * 4 + 1];
                f32x4 s2 = xv * wv[ch * 4 + 2];
                f32x4 s3 = xv * wv[ch * 4 + 3];
#pragma unroll
                for (int l = 0; l < L; ++l) {
                    const f32x4 el = ev[l];
                    if (ch * 4 + 0 != l) s0 = fma4(el, splat4(wm[l * L + ch * 4 + 0]), s0);
                    if (ch * 4 + 1 != l) s1 = fma4(el, splat4(wm[l * L + ch * 4 + 1]), s1);
                    if (ch * 4 + 2 != l) s2 = fma4(el, splat4(wm[l * L + ch * 4 + 2]), s2);
                    if (ch * 4 + 3 != l) s3 = fma4(el, splat4(wm[l * L + ch * 4 + 3]), s3);
                }
                OO[((ch * 4 + 0) << 8) + v] = tanh_zsub4(s0);
                OO[((ch * 4 + 1) << 8) + v] = tanh_zsub4(s1);
                OO[((ch * 4 + 2) << 8) + v] = tanh_zsub4(s2);
                OO[((ch * 4 + 3) << 8) + v] = tanh_zsub4(s3);
            }
        }
    }

    // ---- final: dot with w_e_out straight from registers ----
    if (v < V) {
        f32x4 d = splat4(0.0f);
#pragma unroll
        for (int l = 0; l < L; ++l)
            d = fma4(ev[l], splat4(w_e_out[l]), d);
        const int u0 = blk * 4;
        if (MODE == 0) {
#pragma unroll
            for (int c = 0; c < 4; ++c)
                eo_ws[(size_t)(u0 + c) * V + v] = d[c];
        } else {
#pragma unroll
            for (int c = 0; c < 4; ++c) {
                int j = invp[(pbase + c) * (V + 1) + (v + 1)];
                atomicAdd(&out[b * (V + 1) + j], d[c]);
            }
        }
    }
}

// gather-sum epilogue (MODE 0 path)
__global__ __launch_bounds__(256) void out_kernel(
    const float* __restrict__ x,
    const float* __restrict__ eo_ws,
    const int* __restrict__ perma,
    float* __restrict__ out)
{
    const int b = blockIdx.x;
    const int j = threadIdx.x;   // 0..255
    float acc = x[b * (V + 1) + j];
#pragma unroll
    for (int p = 0; p < P; ++p) {
        int idx = perma[p * (V + 1) + j];
        if (idx > 0) acc += eo_ws[((size_t)(b * P + p)) * V + (idx - 1)];
    }
    out[b * (V + 1) + j] = acc;
}

// fallback helpers (MODE 1 path)
__global__ __launch_bounds__(256) void inv_kernel(const int* __restrict__ perma,
                                                  int* __restrict__ invp)
{
    int p = blockIdx.x, j = threadIdx.x;
    invp[p * (V + 1) + perma[p * (V + 1) + j]] = j;
}

__global__ __launch_bounds__(256) void copy_kernel(const float* __restrict__ x,
                                                   float* __restrict__ out, int n)
{
    int i = blockIdx.x * 256 + threadIdx.x;
    if (i < n) out[i] = x[i];
}

extern "C" void kernel_launch(void* const* d_in, const int* in_sizes, int n_in,
                              void* d_out, int out_size, void* d_ws, size_t ws_size,
                              hipStream_t stream)
{
    const float* x       = (const float*)d_in[0];
    const float* oddw_v  = (const float*)d_in[2];
    const float* oddw_e  = (const float*)d_in[3];
    const float* w_e_out = (const float*)d_in[4];
    const int*   perma   = (const int*)d_in[5];
    const int*   rc      = (const int*)d_in[6];
    const int*   cr      = (const int*)d_in[7];
    float* out = (float*)d_out;

    const int Bx = in_sizes[0] / (V + 1);
    const int nunits = Bx * P;
    const int nquads = nunits / 4;
    const size_t need = (size_t)nunits * V * sizeof(float);

    if (ws_size >= need) {
        float* eo = (float*)d_ws;
        hipLaunchKernelGGL((bpz_kernel<0>), dim3(nquads), dim3(256), 0, stream,
                           x, oddw_v, oddw_e, w_e_out, perma, rc, cr,
                           eo, (const int*)nullptr, (float*)nullptr);
        hipLaunchKernelGGL(out_kernel, dim3(Bx), dim3(256), 0, stream,
                           x, eo, perma, out);
    } else {
        // atomic fallback: needs P*(V+1)*4 = 8KB workspace for inverse perm
        int* invp = (int*)d_ws;
        hipLaunchKernelGGL(inv_kernel, dim3(P), dim3(V + 1), 0, stream, perma, invp);
        hipLaunchKernelGGL(copy_kernel, dim3((out_size + 255) / 256), dim3(256), 0, stream,
                           x, out, out_size);
        hipLaunchKernelGGL((bpz_kernel<1>), dim3(nquads), dim3(256), 0, stream,
                           x, oddw_v, oddw_e, w_e_out, perma, rc, cr,
                           (float*)nullptr, invp, out);
    }
}

// Round 15
// 235.246 us; speedup vs baseline: 1.0555x; 1.0555x over previous
//
#include <hip/hip_runtime.h>

#define V 255
#define L 16
#define P 8
#define CLIPV 10.0f

typedef __attribute__((ext_vector_type(2))) float f32x2;
typedef __attribute__((ext_vector_type(4))) float floatx4;
typedef __attribute__((ext_vector_type(4))) _Float16 half4;

__device__ __forceinline__ f32x2 splat(float a) { return (f32x2){a, a}; }
__device__ __forceinline__ f32x2 pk_fma(f32x2 a, f32x2 b, f32x2 c) {
    return __builtin_elementwise_fma(a, b, c);
}
__device__ __forceinline__ unsigned pkh2(float a, float b) {
    _Float16 ha = (_Float16)a, hb = (_Float16)b;
    return (unsigned)__builtin_bit_cast(unsigned short, ha) |
           ((unsigned)__builtin_bit_cast(unsigned short, hb) << 16);
}
// tanh(0.5*clip(s,-10,10)) = 1 - 2/(exp(clip)+1), then zsub (0 -> 1)
__device__ __forceinline__ float tanh_zsub(float s) {
    float t = fminf(fmaxf(s, -CLIPV), CLIPV);
    float e = __expf(t);
    float o = 1.0f - __fdividef(2.0f, e + 1.0f);
    return (o == 0.0f) ? 1.0f : o;
}

// r12 even phase (f32x2, fused via cr(rc(i))==i) + f16 MFMA odd matvec.
// Layouts: OO f32x2[16][257] (stride-257 pad); A_lds f16 rows [2*256][40B].
// MFMA 16x16x16f16: A lane(row=l&15, k=4(l>>4)+j), B lane(col=l&15, same k),
// D lane(col=l&15, row=4(l>>4)+j)  [C/D layout HW-verified, m89].
// Wave w owns rows [64w,64w+64) = its threads' own v -> A written/consumed
// intra-wave; barriers only for OO and TOT cross-wave deps (3/iter).
template <int MODE>
__global__ __launch_bounds__(256, 2) void bmf_kernel(
    const float* __restrict__ x,
    const float* __restrict__ oddw_v,
    const float* __restrict__ oddw_e,
    const float* __restrict__ w_e_out,
    const int*   __restrict__ perma,
    const int*   __restrict__ rc_idx,
    const int*   __restrict__ cr_idx,
    float* __restrict__ eo_ws,     // MODE 0
    const int* __restrict__ invp,  // MODE 1
    float* __restrict__ out)       // MODE 1
{
    __shared__ f32x2 OO[L * 257];                 // 32.9 KB
    __shared__ f32x2 TOT[257];                    // 2.1 KB
    __shared__ f32x2 XG[256];                     // 2.0 KB
    __shared__ __align__(16) unsigned A_lds[512 * 10];  // 20.5 KB (40B rows)

    const int tid = threadIdx.x;
    const int blk = blockIdx.x;        // pair id
    const int b  = blk >> 2;
    const int pA = (blk & 3) * 2;
    const int pB = pA + 1;
    const int v  = tid;                // 0..255; 255 = dummy (full duty)
    const int vi = (v < V) ? v : (V - 1);
    const int vc = (v < V) ? (v + 1) : V;

    const int lane = tid & 63;
    const int wid  = tid >> 6;
    const int c16  = lane & 15;        // MFMA col / A-row-within-tile
    const int g    = lane >> 4;        // MFMA k-group / row-group

    f32x2 xv;
    {
        const float* xrow = x + b * (V + 1);
        xv.x = xrow[perma[pA * (V + 1) + vc]];
        xv.y = xrow[perma[pB * (V + 1) + vc]];
    }
    XG[v] = xv;

    // packed indices: lo16 = OO elem (cr-gather, stride 257), hi16 = TOT elem
    unsigned pk[L];
    {
        const int4* rc4 = (const int4*)(rc_idx + vi * L);
        const int4* cr4 = (const int4*)(cr_idx + vi * L);
#pragma unroll
        for (int i = 0; i < 4; ++i) {
            int4 a = rc4[i];
            int4 c = cr4[i];
            pk[4*i+0] = ((unsigned)(a.x >> 4) << 16) | ((c.x & 15) * 257 + (c.x >> 4));
            pk[4*i+1] = ((unsigned)(a.y >> 4) << 16) | ((c.y & 15) * 257 + (c.y >> 4));
            pk[4*i+2] = ((unsigned)(a.z >> 4) << 16) | ((c.z & 15) * 257 + (c.z >> 4));
            pk[4*i+3] = ((unsigned)(a.w >> 4) << 16) | ((c.w & 15) * 257 + (c.w >> 4));
        }
    }

    // ---- t=0 odd layer (message==0 -> rank-1), publish zsub'd e ----
#pragma unroll
    for (int m = 0; m < L; ++m) {
        float w0 = oddw_v[m];                      // uniform s_load
        f32x2 e;
        e.x = tanh_zsub(xv.x * w0);
        e.y = tanh_zsub(xv.y * w0);
        OO[m * 257 + v] = e;
    }

    f32x2 ev[L];
#pragma unroll 1
    for (int t = 0; t < 5; ++t) {
        __syncthreads();   // OO complete (init publish or prev MFMA writeback)

        // ---- P1: cr-gather + tree product -> row total ----
        {
            f32x2 t0 = OO[pk[0] & 0xffffu], t1 = OO[pk[1] & 0xffffu];
            f32x2 t2 = OO[pk[2] & 0xffffu], t3 = OO[pk[3] & 0xffffu];
#pragma unroll
            for (int l = 4; l < L; l += 4) {
                t0 = t0 * OO[pk[l + 0] & 0xffffu];
                t1 = t1 * OO[pk[l + 1] & 0xffffu];
                t2 = t2 * OO[pk[l + 2] & 0xffffu];
                t3 = t3 * OO[pk[l + 3] & 0xffffu];
            }
            TOT[v] = (t0 * t1) * (t2 * t3);
        }
        __syncthreads();   // TOT ready

        // ---- P2: fused logratio (own-e re-read from OO): r = T/e;
        // log((1+r)/(1-r+1e-9)+1e-9) == log((e+T)/(e-T+1e-9*e)) to ~1e-6 ----
#pragma unroll
        for (int l = 0; l < L; ++l) {
            f32x2 e  = OO[l * 257 + v];
            f32x2 Tl = TOT[pk[l] >> 16];
            f32x2 num = e + Tl;
            f32x2 den = pk_fma(e, splat(1e-9f), e - Tl);
            f32x2 o;
            o.x = __logf(__fdividef(num.x, den.x));
            o.y = __logf(__fdividef(num.y, den.y));
            ev[l] = o;
        }

        if (t == 4) break;

        // write A rows (f16, 40B stride) for both units
#pragma unroll
        for (int u = 0; u < 2; ++u) {
            unsigned* dst = &A_lds[(u * 256 + v) * 10];
            unsigned aw[8];
#pragma unroll
            for (int q = 0; q < 8; ++q)
                aw[q] = pkh2(ev[2 * q][u], ev[2 * q + 1][u]);
#pragma unroll
            for (int q = 0; q < 4; ++q)
                *(uint2*)(dst + 2 * q) = (uint2){aw[2 * q], aw[2 * q + 1]};
        }
        __syncthreads();   // A + (stale-OK) OO; safe point before writeback

        // ---- P3: per-wave MFMA odd layer (round t+1) ----
        {
            const float* __restrict__ wmn = oddw_e + (t + 1) * (L * L);
            half4 bfrag;
#pragma unroll
            for (int j = 0; j < 4; ++j) {
                int k = 4 * g + j;
                float w = wmn[k * L + c16];
                if (k == c16) w = 0.0f;            // diag mask
                bfrag[j] = (_Float16)w;
            }
            const float wvv = oddw_v[(t + 1) * L + c16];

            const int rowbase = wid * 64;
#pragma unroll
            for (int tt = 0; tt < 4; ++tt) {
                const int rb = rowbase + tt * 16;
                f32x2 xg0 = XG[rb + 4 * g + 0];
                f32x2 xg1 = XG[rb + 4 * g + 1];
                f32x2 xg2 = XG[rb + 4 * g + 2];
                f32x2 xg3 = XG[rb + 4 * g + 3];
#pragma unroll
                for (int u = 0; u < 2; ++u) {
                    uint2 ar = *(const uint2*)
                        &A_lds[(u * 256 + rb + c16) * 10 + g * 2];
                    floatx4 cb;
                    cb[0] = xg0[u] * wvv;
                    cb[1] = xg1[u] * wvv;
                    cb[2] = xg2[u] * wvv;
                    cb[3] = xg3[u] * wvv;
                    floatx4 d = __builtin_amdgcn_mfma_f32_16x16x16f16(
                        __builtin_bit_cast(half4, ar), bfrag, cb, 0, 0, 0);
#pragma unroll
                    for (int j = 0; j < 4; ++j) {
                        float e = tanh_zsub(d[j]);
                        ((float*)OO)[(c16 * 257 + (rb + 4 * g + j)) * 2 + u] = e;
                    }
                }
            }
        }
    }

    // ---- final: dot with w_e_out straight from registers ----
    if (v < V) {
        f32x2 d = splat(0.0f);
#pragma unroll
        for (int l = 0; l < L; ++l)
            d = pk_fma(ev[l], splat(w_e_out[l]), d);
        const int uA = blk * 2;
        if (MODE == 0) {
            eo_ws[(size_t)uA * V + v]       = d.x;
            eo_ws[(size_t)(uA + 1) * V + v] = d.y;
        } else {
            int ja = invp[pA * (V + 1) + (v + 1)];
            int jb = invp[pB * (V + 1) + (v + 1)];
            atomicAdd(&out[b * (V + 1) + ja], d.x);
            atomicAdd(&out[b * (V + 1) + jb], d.y);
        }
    }
}

// gather-sum epilogue (MODE 0 path)
__global__ __launch_bounds__(256) void out_kernel(
    const float* __restrict__ x,
    const float* __restrict__ eo_ws,
    const int* __restrict__ perma,
    float* __restrict__ out)
{
    const int b = blockIdx.x;
    const int j = threadIdx.x;   // 0..255
    float acc = x[b * (V + 1) + j];
#pragma unroll
    for (int p = 0; p < P; ++p) {
        int idx = perma[p * (V + 1) + j];
        if (idx > 0) acc += eo_ws[((size_t)(b * P + p)) * V + (idx - 1)];
    }
    out[b * (V + 1) + j] = acc;
}

// fallback helpers (MODE 1 path)
__global__ __launch_bounds__(256) void inv_kernel(const int* __restrict__ perma,
                                                  int* __restrict__ invp)
{
    int p = blockIdx.x, j = threadIdx.x;
    invp[p * (V + 1) + perma[p * (V + 1) + j]] = j;
}

__global__ __launch_bounds__(256) void copy_kernel(const float* __restrict__ x,
                                                   float* __restrict__ out, int n)
{
    int i = blockIdx.x * 256 + threadIdx.x;
    if (i < n) out[i] = x[i];
}

extern "C" void kernel_launch(void* const* d_in, const int* in_sizes, int n_in,
                              void* d_out, int out_size, void* d_ws, size_t ws_size,
                              hipStream_t stream)
{
    const float* x       = (const float*)d_in[0];
    const float* oddw_v  = (const float*)d_in[2];
    const float* oddw_e  = (const float*)d_in[3];
    const float* w_e_out = (const float*)d_in[4];
    const int*   perma   = (const int*)d_in[5];
    const int*   rc      = (const int*)d_in[6];
    const int*   cr      = (const int*)d_in[7];
    float* out = (float*)d_out;

    const int Bx = in_sizes[0] / (V + 1);
    const int nunits = Bx * P;
    const int npairs = nunits / 2;
    const size_t need = (size_t)nunits * V * sizeof(float);

    if (ws_size >= need) {
        float* eo = (float*)d_ws;
        hipLaunchKernelGGL((bmf_kernel<0>), dim3(npairs), dim3(256), 0, stream,
                           x, oddw_v, oddw_e, w_e_out, perma, rc, cr,
                           eo, (const int*)nullptr, (float*)nullptr);
        hipLaunchKernelGGL(out_kernel, dim3(Bx), dim3(256), 0, stream,
                           x, eo, perma, out);
    } else {
        // atomic fallback: needs P*(V+1)*4 = 8KB workspace for inverse perm
        int* invp = (int*)d_ws;
        hipLaunchKernelGGL(inv_kernel, dim3(P), dim3(V + 1), 0, stream, perma, invp);
        hipLaunchKernelGGL(copy_kernel, dim3((out_size + 255) / 256), dim3(256), 0, stream,
                           x, out, out_size);
        hipLaunchKernelGGL((bmf_kernel<1>), dim3(npairs), dim3(256), 0, stream,
                           x, oddw_v, oddw_e, w_e_out, perma, rc, cr,
                           (float*)nullptr, invp, out);
    }
}